// Round 7
// baseline (211.711 us; speedup 1.0000x reference)
//
#include <hip/hip_runtime.h>
#include <hip/hip_bf16.h>

#define NEG_INF (-9999999.0f)

typedef __attribute__((ext_vector_type(8))) short bf16x8;
typedef __attribute__((ext_vector_type(4))) float f32x4;
typedef unsigned short us;

__device__ __forceinline__ float b2f(us u) {
  union { unsigned int i; float f; } x; x.i = ((unsigned int)u) << 16; return x.f;
}
__device__ __forceinline__ us f2b(float f) {
  union { float f; unsigned int i; } x; x.f = f;
  unsigned int r = x.i + 0x7fffu + ((x.i >> 16) & 1u);
  return (us)(r >> 16);
}
__device__ __forceinline__ float lrelu(float v) { return v > 0.f ? v : 0.01f * v; }
__device__ __forceinline__ bf16x8 ld8(const us* p) { return *reinterpret_cast<const bf16x8*>(p); }

// wave -> (first n-tile, count) for a 19-tile N dimension split across (y, w)
__device__ __forceinline__ void ntile_assign(int y, int w, int& nt0, int& cnt) {
  if (y == 0) { nt0 = (w < 2) ? 3 * w : 6 + 2 * (w - 2); cnt = (w < 2) ? 3 : 2; }
  else        { nt0 = (w == 0) ? 10 : 13 + 2 * (w - 1);  cnt = (w == 0) ? 3 : 2; }
}

// ---------------- prep ----------------
__global__ __launch_bounds__(256) void k_prep(const int* __restrict__ wi, const float* __restrict__ E,
    const float* __restrict__ Ws, const float* __restrict__ Wp, const float* __restrict__ Wc,
    const float* __restrict__ Wr,
    us* __restrict__ Wsb, us* __restrict__ Wpb, us* __restrict__ Wcb, us* __restrict__ Wrb,
    us* __restrict__ xg, us* __restrict__ encb, us* __restrict__ Pb, us* __restrict__ Cb,
    us* __restrict__ encTb) {
  int task = blockIdx.y;
  int gid = blockIdx.x * 256 + threadIdx.x;
  const int stride = 640 * 256;
  if (task < 3) {
    const float* src = (task == 0) ? Ws : (task == 1) ? Wp : Wc;
    us* dst = (task == 0) ? Wsb : (task == 1) ? Wpb : Wcb;
    for (int i = gid; i < 304 * 320; i += stride) {
      int r = i / 320, c = i - r * 320;
      dst[i] = (r < 300 && c < 300) ? f2b(src[r * 300 + c]) : 0;
    }
  } else if (task == 3) {
    for (int i = gid; i < 304 * 928; i += stride) {
      int r = i / 928, c = i - r * 928;
      Wrb[i] = (r < 300 && c < 900) ? f2b(Wr[r * 900 + c]) : 0;
    }
  } else if (task == 4) {
    for (int i = gid; i < 4096 * 320; i += stride) {
      int r = i / 320, c = i - r * 320;
      xg[i] = (c < 300) ? f2b(E[(long)wi[r * 64 + 63] * 300 + c]) : 0;
    }
  } else if (task == 5) {
    for (int i = gid; i < 3 * 4096 * 20; i += stride) {
      int b = i / 81920, rem = i - b * 81920;
      int r = rem / 20, c = 300 + (rem - r * 20);
      us* dst = (b == 0) ? encb : (b == 1) ? Pb : Cb;
      dst[r * 320 + c] = 0;
    }
  } else {
    for (int i = gid; i < 4 * 4096; i += stride)
      encTb[300 * 4096 + i] = 0;
  }
}

// ---------------- MFMA sweep: 16 m-rows x NT n-tiles, prefetch depth 2 ----------------
template<int NT>
__device__ __forceinline__ void sweep(const us* __restrict__ Ab, int apitch,
    const us* __restrict__ Bb, int bpitch, int m0, int nt0, int lo, int q,
    int ks0, int ksn, f32x4* acc) {
  const us* ar = Ab + (long)(m0 + lo) * apitch + 8 * q + (long)ks0 * 32;
  const us* br[NT];
#pragma unroll
  for (int t = 0; t < NT; ++t)
    br[t] = Bb + (long)((nt0 + t) * 16 + lo) * bpitch + 8 * q + (long)ks0 * 32;
  bf16x8 a0 = ld8(ar), a1 = ld8(ar + 32);
  bf16x8 b0[NT], b1[NT];
#pragma unroll
  for (int t = 0; t < NT; ++t) b0[t] = ld8(br[t]);
#pragma unroll
  for (int t = 0; t < NT; ++t) b1[t] = ld8(br[t] + 32);
  for (int ks = 0; ks < ksn - 2; ++ks) {
    bf16x8 a2 = ld8(ar + (ks + 2) * 32);
    bf16x8 b2[NT];
#pragma unroll
    for (int t = 0; t < NT; ++t) b2[t] = ld8(br[t] + (ks + 2) * 32);
#pragma unroll
    for (int t = 0; t < NT; ++t)
      acc[t] = __builtin_amdgcn_mfma_f32_16x16x32_bf16(a0, b0[t], acc[t], 0, 0, 0);
    a0 = a1; a1 = a2;
#pragma unroll
    for (int t = 0; t < NT; ++t) { b0[t] = b1[t]; b1[t] = b2[t]; }
  }
#pragma unroll
  for (int t = 0; t < NT; ++t)
    acc[t] = __builtin_amdgcn_mfma_f32_16x16x32_bf16(a0, b0[t], acc[t], 0, 0, 0);
#pragma unroll
  for (int t = 0; t < NT; ++t)
    acc[t] = __builtin_amdgcn_mfma_f32_16x16x32_bf16(a1, b1[t], acc[t], 0, 0, 0);
}

template<int NT>
__device__ __forceinline__ void epi_bf16(const f32x4* acc, const float* __restrict__ bias,
    us* __restrict__ outb, us* __restrict__ outT,
    int m0, int nt0, int lo, int q) {
#pragma unroll
  for (int t = 0; t < NT; ++t) {
    int col = (nt0 + t) * 16 + lo;
    if (col >= 300) continue;
    float bb = bias[col];
#pragma unroll
    for (int r = 0; r < 4; ++r) {
      int row = m0 + q * 4 + r;
      us h = f2b(lrelu(acc[t][r] + bb));
      outb[(long)row * 320 + col] = h;
      if (outT) outT[(long)col * 4096 + row] = h;
    }
  }
}

// ---------------- enc GEMM: grid (256 m, 2 n-groups), bf16 epi + transpose ----------------
__global__ __launch_bounds__(256, 2) void k_gemm_enc(const us* __restrict__ Ab,
    const us* __restrict__ Bb, const float* __restrict__ bias,
    us* __restrict__ encb, us* __restrict__ encTb) {
  int w = threadIdx.x >> 6, lane = threadIdx.x & 63;
  int lo = lane & 15, q = lane >> 4;
  int m0 = blockIdx.x * 16;
  int nt0, cnt;
  ntile_assign(blockIdx.y, w, nt0, cnt);
  f32x4 z = {0.f, 0.f, 0.f, 0.f};
  if (cnt == 3) {
    f32x4 acc[3] = {z, z, z};
    sweep<3>(Ab, 320, Bb, 320, m0, nt0, lo, q, 0, 10, acc);
    epi_bf16<3>(acc, bias, encb, encTb, m0, nt0, lo, q);
  } else {
    f32x4 acc[2] = {z, z};
    sweep<2>(Ab, 320, Bb, 320, m0, nt0, lo, q, 0, 10, acc);
    epi_bf16<2>(acc, bias, encb, encTb, m0, nt0, lo, q);
  }
}

// ---------------- P/C GEMM: grid (256 m, 2 n-groups, 2 which) ----------------
__global__ __launch_bounds__(256, 2) void k_gemm_pc(const us* __restrict__ Ab,
    const us* __restrict__ Wpb, const us* __restrict__ Wcb,
    const float* __restrict__ bp, const float* __restrict__ bc,
    us* __restrict__ Pb, us* __restrict__ Cb) {
  int which = blockIdx.z;
  const us* Bb = which ? Wcb : Wpb;
  const float* bias = which ? bc : bp;
  us* outb = which ? Cb : Pb;
  int w = threadIdx.x >> 6, lane = threadIdx.x & 63;
  int lo = lane & 15, q = lane >> 4;
  int m0 = blockIdx.x * 16;
  int nt0, cnt;
  ntile_assign(blockIdx.y, w, nt0, cnt);
  f32x4 z = {0.f, 0.f, 0.f, 0.f};
  if (cnt == 3) {
    f32x4 acc[3] = {z, z, z};
    sweep<3>(Ab, 320, Bb, 320, m0, nt0, lo, q, 0, 10, acc);
    epi_bf16<3>(acc, bias, outb, (us*)nullptr, m0, nt0, lo, q);
  } else {
    f32x4 acc[2] = {z, z};
    sweep<2>(Ab, 320, Bb, 320, m0, nt0, lo, q, 0, 10, acc);
    epi_bf16<2>(acc, bias, outb, (us*)nullptr, m0, nt0, lo, q);
  }
}

// ---------------- fused attn + fri + glue, one block per doc ----------------
__global__ __launch_bounds__(256) void k_ag(
    const us* __restrict__ Pb, const us* __restrict__ Cb,
    const us* __restrict__ encb, const us* __restrict__ encTb,
    const float* __restrict__ w_root, const float* __restrict__ b_root,
    const float* __restrict__ root,
    float* __restrict__ Aout, float* __restrict__ outF, us* __restrict__ ub) {
  __shared__ float Ls[64][65];
  __shared__ __align__(16) us At[64][72];
  __shared__ float pm[4][64], psum[4][64];
  __shared__ float scores[64], frs[64], rs[64];
  int d = blockIdx.x, t = threadIdx.x;

  // phase A: fri scores (4 threads per row)
  {
    int rr = t >> 2, quad = t & 3;
    const us* er = encb + (long)(d * 64 + rr) * 320;
    float s = 0.f;
    for (int h = quad * 4; h + 4 <= 300; h += 16) {
      ushort4 e4 = *reinterpret_cast<const ushort4*>(er + h);
      s = fmaf(b2f(e4.x), w_root[h], s);
      s = fmaf(b2f(e4.y), w_root[h + 1], s);
      s = fmaf(b2f(e4.z), w_root[h + 2], s);
      s = fmaf(b2f(e4.w), w_root[h + 3], s);
    }
    s += __shfl_xor(s, 1);
    s += __shfl_xor(s, 2);
    if (quad == 0) scores[rr] = s + b_root[0];
  }
  __syncthreads();
  if (t < 64) {
    float s = scores[t];
    float m = s;
#pragma unroll
    for (int o = 32; o > 0; o >>= 1) m = fmaxf(m, __shfl_xor(m, o, 64));
    float e = expf(s - m);
    float sum = e;
#pragma unroll
    for (int o = 32; o > 0; o >>= 1) sum += __shfl_xor(sum, o, 64);
    float f = e / sum;
    outF[d * 64 + t] = f;
    frs[t] = f;
  }

  // phase B: logits = P . C^T
  int w = t >> 6, lane = t & 63, lo = lane & 15, q = lane >> 4;
  {
    const us* Pd = Pb + (long)d * 64 * 320;
    const us* Cd = Cb + (long)d * 64 * 320;
    f32x4 z = {0.f, 0.f, 0.f, 0.f};
    f32x4 acc[4] = {z, z, z, z};
    sweep<4>(Pd, 320, Cd, 320, w * 16, 0, lo, q, 0, 10, acc);
#pragma unroll
    for (int t2 = 0; t2 < 4; ++t2) {
#pragma unroll
      for (int r = 0; r < 4; ++r) {
        int i = w * 16 + q * 4 + r, j = t2 * 16 + lo;
        Ls[i][j] = (i == j) ? NEG_INF : acc[t2][r];
      }
    }
  }
  __syncthreads();

  // phase C: column softmax over i; write Aout, At (LDS), Ls := A
  {
    int j = t & 63, p = t >> 6;
    float mx = -3.0e38f;
    for (int i = p * 16; i < p * 16 + 16; ++i) mx = fmaxf(mx, Ls[i][j]);
    pm[p][j] = mx;
    __syncthreads();
    float gmx = fmaxf(fmaxf(pm[0][j], pm[1][j]), fmaxf(pm[2][j], pm[3][j]));
    float s = 0.f;
    for (int i = p * 16; i < p * 16 + 16; ++i) s += expf(Ls[i][j] - gmx);
    psum[p][j] = s;
    __syncthreads();
    float inv = 1.f / (psum[0][j] + psum[1][j] + psum[2][j] + psum[3][j]);
    float* Ad = Aout + (long)d * 4096;
    for (int i = p * 16; i < p * 16 + 16; ++i) {
      float a = expf(Ls[i][j] - gmx) * inv;
      Ad[i * 64 + j] = a;
      At[j][i] = f2b(a);
      Ls[i][j] = a;
    }
  }
  __syncthreads();
  if (t < 64) {
    float s = 0.f;
    for (int j2 = 0; j2 < 64; ++j2) s += Ls[t][j2];
    rs[t] = s;
  }
  __syncthreads();

  // phase D: tmp = A^T . enc (At from LDS, enc^T from global, B-prefetch), build ub
  {
    bf16x8 av0 = *reinterpret_cast<const bf16x8*>(&At[w * 16 + lo][8 * q]);
    bf16x8 av1 = *reinterpret_cast<const bf16x8*>(&At[w * 16 + lo][32 + 8 * q]);
    const us* brow = encTb + (long)lo * 4096 + d * 64 + 8 * q;
    bf16x8 bv0 = ld8(brow), bv1 = ld8(brow + 32);
    for (int nt = 0; nt < 19; ++nt) {
      bf16x8 nb0, nb1;
      if (nt < 18) {
        const us* nrow = encTb + (long)((nt + 1) * 16 + lo) * 4096 + d * 64 + 8 * q;
        nb0 = ld8(nrow); nb1 = ld8(nrow + 32);
      }
      f32x4 acc = {0.f, 0.f, 0.f, 0.f};
      acc = __builtin_amdgcn_mfma_f32_16x16x32_bf16(av0, bv0, acc, 0, 0, 0);
      acc = __builtin_amdgcn_mfma_f32_16x16x32_bf16(av1, bv1, acc, 0, 0, 0);
      int h = nt * 16 + lo;
      if (h < 300) {
        float rt = root[h];
#pragma unroll
        for (int r = 0; r < 4; ++r) {
          int i = w * 16 + q * 4 + r;
          ub[(long)(d * 64 + i) * 928 + 300 + h] = f2b(acc[r] + frs[i] * rt);
        }
      }
      bv0 = nb0; bv1 = nb1;
    }
  }
  for (int idx = t; idx < 64 * 300; idx += 256) {
    int r = idx / 300, c = idx - r * 300;
    us ev = encb[(long)(d * 64 + r) * 320 + c];
    ub[(long)(d * 64 + r) * 928 + c] = ev;
    ub[(long)(d * 64 + r) * 928 + 600 + c] = f2b(b2f(ev) * rs[r]);
  }
  for (int idx = t; idx < 64 * 28; idx += 256) {
    int r = idx / 28, c = 900 + (idx - r * 28);
    ub[(long)(d * 64 + r) * 928 + c] = 0;
  }
}

// ---------------- ri GEMM: grid (256 m, 2 n-groups), K=29, fused bias+lrelu fp32 epi ----------------
__global__ __launch_bounds__(256, 2) void k_gemm_ri(const us* __restrict__ Ab,
    const us* __restrict__ Bb, const float* __restrict__ bias, float* __restrict__ ri) {
  int w = threadIdx.x >> 6, lane = threadIdx.x & 63;
  int lo = lane & 15, q = lane >> 4;
  int m0 = blockIdx.x * 16;
  int nt0, cnt;
  ntile_assign(blockIdx.y, w, nt0, cnt);
  f32x4 z = {0.f, 0.f, 0.f, 0.f};
  f32x4 acc[3] = {z, z, z};
  if (cnt == 3) sweep<3>(Ab, 928, Bb, 928, m0, nt0, lo, q, 0, 29, acc);
  else          sweep<2>(Ab, 928, Bb, 928, m0, nt0, lo, q, 0, 29, acc);
  for (int t2 = 0; t2 < cnt; ++t2) {
    int col = (nt0 + t2) * 16 + lo;
    if (col >= 300) continue;
    float bb = bias[col];
#pragma unroll
    for (int r = 0; r < 4; ++r)
      ri[(long)(m0 + q * 4 + r) * 300 + col] = lrelu(acc[t2][r] + bb);
  }
}

// ---------------- final ----------------
__global__ __launch_bounds__(256) void k_final(const float* __restrict__ ri,
    const float* __restrict__ W_cls, const float* __restrict__ b_cls,
    float* __restrict__ outp) {
  __shared__ float fin[300];
  __shared__ float red[256];
  int d = blockIdx.x, t = threadIdx.x;
  for (int h = t; h < 300; h += 256) {
    float s = 0.f;
    for (int i = 0; i < 64; ++i) s += ri[((d * 64) + i) * 300 + h];
    fin[h] = s * (1.0f / 64.0f);
  }
  __syncthreads();
  for (int c2 = 0; c2 < 2; ++c2) {
    float pth = 0.f;
    for (int h = t; h < 300; h += 256) pth = fmaf(fin[h], W_cls[c2 * 300 + h], pth);
    red[t] = pth;
    __syncthreads();
    for (int o = 128; o > 0; o >>= 1) {
      if (t < o) red[t] += red[t + o];
      __syncthreads();
    }
    if (t == 0) outp[d * 2 + c2] = red[0] + b_cls[c2];
    __syncthreads();
  }
}

extern "C" void kernel_launch(void* const* d_in, const int* in_sizes, int n_in,
                              void* d_out, int out_size, void* d_ws, size_t ws_size,
                              hipStream_t stream) {
  const int*   wi     = (const int*)d_in[0];
  const float* E      = (const float*)d_in[1];
  const float* W_sent = (const float*)d_in[2];
  const float* b_sent = (const float*)d_in[3];
  const float* W_par  = (const float*)d_in[4];
  const float* b_par  = (const float*)d_in[5];
  const float* W_ch   = (const float*)d_in[6];
  const float* b_ch   = (const float*)d_in[7];
  const float* w_root = (const float*)d_in[8];
  const float* b_root = (const float*)d_in[9];
  const float* root_e = (const float*)d_in[10];
  const float* W_r    = (const float*)d_in[11];
  const float* b_r    = (const float*)d_in[12];
  const float* W_cls  = (const float*)d_in[13];
  const float* b_cls  = (const float*)d_in[14];

  us* B = (us*)d_ws;
  us* Wsb   = B;                 //  97280   [304][320]
  us* Wpb   = B + 97280;
  us* Wcb   = B + 194560;
  us* Wrb   = B + 291840;        // 282112   [304][928]
  us* xg    = B + 573952;        // 1310720  [4096][320]
  us* encb  = B + 1884672;       // 1310720
  us* encTb = B + 3195392;       // 1245184  [304][4096]
  us* Pb    = B + 4440576;       // 1310720
  us* Cb    = B + 5751296;       // 1310720
  us* ub    = B + 7062016;       // 3801088  [4096][928]
  float* ri = (float*)(B + 10863104);  // [4096][300] fp32

  float* outp = (float*)d_out;   // [out(128) | A(262144) | fri(4096)]
  float* outA = outp + 128;
  float* outF = outp + 128 + 262144;

  k_prep<<<dim3(640, 7), 256, 0, stream>>>(wi, E, W_sent, W_par, W_ch, W_r,
                                           Wsb, Wpb, Wcb, Wrb, xg, encb, Pb, Cb, encTb);
  k_gemm_enc<<<dim3(256, 2), 256, 0, stream>>>(xg, Wsb, b_sent, encb, encTb);
  k_gemm_pc<<<dim3(256, 2, 2), 256, 0, stream>>>(encb, Wpb, Wcb, b_par, b_ch, Pb, Cb);
  k_ag<<<64, 256, 0, stream>>>(Pb, Cb, encb, encTb, w_root, b_root, root_e,
                               outA, outF, ub);
  k_gemm_ri<<<dim3(256, 2), 256, 0, stream>>>(ub, Wrb, b_r, ri);
  k_final<<<64, 256, 0, stream>>>(ri, W_cls, b_cls, outp);
}

// Round 8
// 191.594 us; speedup vs baseline: 1.1050x; 1.1050x over previous
//
#include <hip/hip_runtime.h>
#include <hip/hip_bf16.h>

#define NEG_INF (-9999999.0f)

typedef __attribute__((ext_vector_type(8))) short bf16x8;
typedef __attribute__((ext_vector_type(4))) float f32x4;
typedef unsigned short us;

__device__ __forceinline__ float b2f(us u) {
  union { unsigned int i; float f; } x; x.i = ((unsigned int)u) << 16; return x.f;
}
__device__ __forceinline__ us f2b(float f) {
  union { float f; unsigned int i; } x; x.f = f;
  unsigned int r = x.i + 0x7fffu + ((x.i >> 16) & 1u);
  return (us)(r >> 16);
}
__device__ __forceinline__ float lrelu(float v) { return v > 0.f ? v : 0.01f * v; }
__device__ __forceinline__ bf16x8 ld8(const us* p) { return *reinterpret_cast<const bf16x8*>(p); }

// ---------------- prep ----------------
__global__ __launch_bounds__(256) void k_prep(const int* __restrict__ wi, const float* __restrict__ E,
    const float* __restrict__ Ws, const float* __restrict__ Wp, const float* __restrict__ Wc,
    const float* __restrict__ Wr,
    us* __restrict__ Wsb, us* __restrict__ Wpb, us* __restrict__ Wcb, us* __restrict__ Wrb,
    us* __restrict__ xg, us* __restrict__ encb, us* __restrict__ Pb, us* __restrict__ Cb,
    us* __restrict__ encTb) {
  int task = blockIdx.y;
  int gid = blockIdx.x * 256 + threadIdx.x;
  const int stride = 640 * 256;
  if (task < 3) {
    const float* src = (task == 0) ? Ws : (task == 1) ? Wp : Wc;
    us* dst = (task == 0) ? Wsb : (task == 1) ? Wpb : Wcb;
    for (int i = gid; i < 304 * 320; i += stride) {
      int r = i / 320, c = i - r * 320;
      dst[i] = (r < 300 && c < 300) ? f2b(src[r * 300 + c]) : 0;
    }
  } else if (task == 3) {
    for (int i = gid; i < 304 * 928; i += stride) {
      int r = i / 928, c = i - r * 928;
      Wrb[i] = (r < 300 && c < 900) ? f2b(Wr[r * 900 + c]) : 0;
    }
  } else if (task == 4) {
    for (int i = gid; i < 4096 * 320; i += stride) {
      int r = i / 320, c = i - r * 320;
      xg[i] = (c < 300) ? f2b(E[(long)wi[r * 64 + 63] * 300 + c]) : 0;
    }
  } else if (task == 5) {
    for (int i = gid; i < 3 * 4096 * 20; i += stride) {
      int b = i / 81920, rem = i - b * 81920;
      int r = rem / 20, c = 300 + (rem - r * 20);
      us* dst = (b == 0) ? encb : (b == 1) ? Pb : Cb;
      dst[r * 320 + c] = 0;
    }
  } else {
    for (int i = gid; i < 4 * 4096; i += stride)
      encTb[300 * 4096 + i] = 0;
  }
}

// ---------------- MFMA sweep: 16 m-rows x NT n-tiles, prefetch depth 2 ----------------
template<int NT>
__device__ __forceinline__ void sweep(const us* __restrict__ Ab, int apitch,
    const us* __restrict__ Bb, int bpitch, int m0, int nt0, int lo, int q,
    int ks0, int ksn, f32x4* acc) {
  const us* ar = Ab + (long)(m0 + lo) * apitch + 8 * q + (long)ks0 * 32;
  const us* br[NT];
#pragma unroll
  for (int t = 0; t < NT; ++t)
    br[t] = Bb + (long)((nt0 + t) * 16 + lo) * bpitch + 8 * q + (long)ks0 * 32;
  bf16x8 a0 = ld8(ar), a1 = ld8(ar + 32);
  bf16x8 b0[NT], b1[NT];
#pragma unroll
  for (int t = 0; t < NT; ++t) b0[t] = ld8(br[t]);
#pragma unroll
  for (int t = 0; t < NT; ++t) b1[t] = ld8(br[t] + 32);
  for (int ks = 0; ks < ksn - 2; ++ks) {
    bf16x8 a2 = ld8(ar + (ks + 2) * 32);
    bf16x8 b2[NT];
#pragma unroll
    for (int t = 0; t < NT; ++t) b2[t] = ld8(br[t] + (ks + 2) * 32);
#pragma unroll
    for (int t = 0; t < NT; ++t)
      acc[t] = __builtin_amdgcn_mfma_f32_16x16x32_bf16(a0, b0[t], acc[t], 0, 0, 0);
    a0 = a1; a1 = a2;
#pragma unroll
    for (int t = 0; t < NT; ++t) { b0[t] = b1[t]; b1[t] = b2[t]; }
  }
#pragma unroll
  for (int t = 0; t < NT; ++t)
    acc[t] = __builtin_amdgcn_mfma_f32_16x16x32_bf16(a0, b0[t], acc[t], 0, 0, 0);
#pragma unroll
  for (int t = 0; t < NT; ++t)
    acc[t] = __builtin_amdgcn_mfma_f32_16x16x32_bf16(a1, b1[t], acc[t], 0, 0, 0);
}

template<int NT>
__device__ __forceinline__ void epi_bf16(const f32x4* acc, const float* __restrict__ bias,
    us* __restrict__ outb, us* __restrict__ outT,
    int m0, int nt0, int lo, int q) {
#pragma unroll
  for (int t = 0; t < NT; ++t) {
    int col = (nt0 + t) * 16 + lo;
    if (col >= 300) continue;
    float bb = bias[col];
#pragma unroll
    for (int r = 0; r < 4; ++r) {
      int row = m0 + q * 4 + r;
      us h = f2b(lrelu(acc[t][r] + bb));
      outb[(long)row * 320 + col] = h;
      if (outT) outT[(long)col * 4096 + row] = h;
    }
  }
}

// ---------------- enc GEMM ----------------
__global__ __launch_bounds__(256) void k_gemm_enc(const us* __restrict__ Ab,
    const us* __restrict__ Bb, const float* __restrict__ bias,
    us* __restrict__ encb, us* __restrict__ encTb) {
  int w = threadIdx.x >> 6, lane = threadIdx.x & 63;
  int lo = lane & 15, q = lane >> 4;
  int m0 = blockIdx.x * 16;
  f32x4 z = {0.f, 0.f, 0.f, 0.f};
  if (w < 3) {
    f32x4 acc[5] = {z, z, z, z, z};
    sweep<5>(Ab, 320, Bb, 320, m0, w * 5, lo, q, 0, 10, acc);
    epi_bf16<5>(acc, bias, encb, encTb, m0, w * 5, lo, q);
  } else {
    f32x4 acc[4] = {z, z, z, z};
    sweep<4>(Ab, 320, Bb, 320, m0, 15, lo, q, 0, 10, acc);
    epi_bf16<4>(acc, bias, encb, encTb, m0, 15, lo, q);
  }
}

// ---------------- P/C GEMM ----------------
__global__ __launch_bounds__(256) void k_gemm_pc(const us* __restrict__ Ab,
    const us* __restrict__ Wpb, const us* __restrict__ Wcb,
    const float* __restrict__ bp, const float* __restrict__ bc,
    us* __restrict__ Pb, us* __restrict__ Cb) {
  int which = blockIdx.y;
  const us* Bb = which ? Wcb : Wpb;
  const float* bias = which ? bc : bp;
  us* outb = which ? Cb : Pb;
  int w = threadIdx.x >> 6, lane = threadIdx.x & 63;
  int lo = lane & 15, q = lane >> 4;
  int m0 = blockIdx.x * 16;
  f32x4 z = {0.f, 0.f, 0.f, 0.f};
  if (w < 3) {
    f32x4 acc[5] = {z, z, z, z, z};
    sweep<5>(Ab, 320, Bb, 320, m0, w * 5, lo, q, 0, 10, acc);
    epi_bf16<5>(acc, bias, outb, (us*)nullptr, m0, w * 5, lo, q);
  } else {
    f32x4 acc[4] = {z, z, z, z};
    sweep<4>(Ab, 320, Bb, 320, m0, 15, lo, q, 0, 10, acc);
    epi_bf16<4>(acc, bias, outb, (us*)nullptr, m0, 15, lo, q);
  }
}

// ---------------- attn: block (d, jg) owns a 64x16 logit slab; local column softmax ----------------
__global__ __launch_bounds__(256) void k_attn(
    const us* __restrict__ Pb, const us* __restrict__ Cb, const us* __restrict__ encb,
    const float* __restrict__ w_root, const float* __restrict__ b_root,
    float* __restrict__ Aout, float* __restrict__ outF,
    us* __restrict__ Atb, float* __restrict__ rsp) {
  __shared__ float Ls[64][17];
  __shared__ float pm[4][16], psum[4][16];
  __shared__ float scores[64];
  int d = blockIdx.x, jg = blockIdx.y, t = threadIdx.x;
  int w = t >> 6, lane = t & 63, lo = lane & 15, q = lane >> 4;

  // fri scores (all blocks compute, jg==0 writes)
  {
    int rr = t >> 2, quad = t & 3;
    const us* er = encb + (long)(d * 64 + rr) * 320;
    float s = 0.f;
    for (int h = quad * 4; h + 4 <= 300; h += 16) {
      ushort4 e4 = *reinterpret_cast<const ushort4*>(er + h);
      s = fmaf(b2f(e4.x), w_root[h], s);
      s = fmaf(b2f(e4.y), w_root[h + 1], s);
      s = fmaf(b2f(e4.z), w_root[h + 2], s);
      s = fmaf(b2f(e4.w), w_root[h + 3], s);
    }
    s += __shfl_xor(s, 1);
    s += __shfl_xor(s, 2);
    if (quad == 0) scores[rr] = s + b_root[0];
  }
  __syncthreads();
  if (jg == 0 && t < 64) {
    float s = scores[t];
    float m = s;
#pragma unroll
    for (int o = 32; o > 0; o >>= 1) m = fmaxf(m, __shfl_xor(m, o, 64));
    float e = expf(s - m);
    float sum = e;
#pragma unroll
    for (int o = 32; o > 0; o >>= 1) sum += __shfl_xor(sum, o, 64);
    outF[d * 64 + t] = e / sum;
  }

  // logits: wave w -> m-tile w, single n-tile jg
  {
    const us* Pd = Pb + (long)d * 64 * 320;
    const us* Cd = Cb + (long)d * 64 * 320;
    f32x4 acc = {0.f, 0.f, 0.f, 0.f};
    sweep<1>(Pd, 320, Cd, 320, w * 16, jg, lo, q, 0, 10, &acc);
#pragma unroll
    for (int r = 0; r < 4; ++r) {
      int i = w * 16 + q * 4 + r, j = jg * 16 + lo;
      Ls[i][lo] = (i == j) ? NEG_INF : acc[r];
    }
  }
  __syncthreads();

  // column softmax over i, 16 columns
  {
    int col = t & 15, p = t >> 4;
    if (t < 64) {
      float mx = -3.0e38f;
      for (int i = p * 16; i < p * 16 + 16; ++i) mx = fmaxf(mx, Ls[i][col]);
      pm[p][col] = mx;
    }
    __syncthreads();
    if (t < 64) {
      float gmx = fmaxf(fmaxf(pm[0][col], pm[1][col]), fmaxf(pm[2][col], pm[3][col]));
      float s = 0.f;
      for (int i = p * 16; i < p * 16 + 16; ++i) s += expf(Ls[i][col] - gmx);
      psum[p][col] = s;
    }
    __syncthreads();
    if (t < 64) {
      float gmx = fmaxf(fmaxf(pm[0][col], pm[1][col]), fmaxf(pm[2][col], pm[3][col]));
      float inv = 1.f / (psum[0][col] + psum[1][col] + psum[2][col] + psum[3][col]);
      int j = jg * 16 + col;
      float* Ad = Aout + (long)d * 4096;
      us* Atd = Atb + (long)d * 4096;
      for (int i = p * 16; i < p * 16 + 16; ++i) {
        float a = expf(Ls[i][col] - gmx) * inv;
        Ad[i * 64 + j] = a;
        Atd[j * 64 + i] = f2b(a);   // At[x][y] = A[y][x]
        Ls[i][col] = a;
      }
    }
  }
  __syncthreads();
  if (t < 64) {
    float s = 0.f;
#pragma unroll
    for (int c = 0; c < 16; ++c) s += Ls[t][c];
    rsp[(d * 4 + jg) * 64 + t] = s;
  }
}

// ---------------- glue2: block (d, g); wave w -> h-tile g*4+w; 60-col seg0/seg2 slice ----------------
__global__ __launch_bounds__(256) void k_glue2(
    const us* __restrict__ Atb, const us* __restrict__ encTb, const us* __restrict__ encb,
    const float* __restrict__ outF, const float* __restrict__ rsp,
    const float* __restrict__ root, us* __restrict__ ub) {
  __shared__ float frs[64], rs[64];
  int d = blockIdx.x, g = blockIdx.y, t = threadIdx.x;
  if (t < 64) {
    frs[t] = outF[d * 64 + t];
    rs[t] = rsp[(d * 4 + 0) * 64 + t] + rsp[(d * 4 + 1) * 64 + t]
          + rsp[(d * 4 + 2) * 64 + t] + rsp[(d * 4 + 3) * 64 + t];
  }
  __syncthreads();
  int w = t >> 6, lane = t & 63, lo = lane & 15, q = lane >> 4;
  int ht = g * 4 + w;
  if (ht < 19) {
    const us* Atd = Atb + (long)d * 4096;
    bf16x8 av0[4], av1[4];
#pragma unroll
    for (int mt = 0; mt < 4; ++mt) {
      av0[mt] = ld8(Atd + (mt * 16 + lo) * 64 + 8 * q);
      av1[mt] = ld8(Atd + (mt * 16 + lo) * 64 + 32 + 8 * q);
    }
    const us* brow = encTb + (long)(ht * 16 + lo) * 4096 + d * 64 + 8 * q;
    bf16x8 bv0 = ld8(brow), bv1 = ld8(brow + 32);
    int h = ht * 16 + lo;
    float rt = (h < 300) ? root[h] : 0.f;
#pragma unroll
    for (int mt = 0; mt < 4; ++mt) {
      f32x4 acc = {0.f, 0.f, 0.f, 0.f};
      acc = __builtin_amdgcn_mfma_f32_16x16x32_bf16(av0[mt], bv0, acc, 0, 0, 0);
      acc = __builtin_amdgcn_mfma_f32_16x16x32_bf16(av1[mt], bv1, acc, 0, 0, 0);
      if (h < 300) {
#pragma unroll
        for (int r = 0; r < 4; ++r) {
          int i = mt * 16 + q * 4 + r;
          ub[(long)(d * 64 + i) * 928 + 300 + h] = f2b(acc[r] + frs[i] * rt);
        }
      }
    }
  }
  for (int idx = t; idx < 64 * 60; idx += 256) {
    int r = idx / 60, c = g * 60 + (idx - (idx / 60) * 60);
    us ev = encb[(long)(d * 64 + r) * 320 + c];
    ub[(long)(d * 64 + r) * 928 + c] = ev;
    ub[(long)(d * 64 + r) * 928 + 600 + c] = f2b(b2f(ev) * rs[r]);
  }
  if (g == 4) {
    for (int idx = t; idx < 64 * 28; idx += 256) {
      int r = idx / 28, c = 900 + (idx - r * 28);
      ub[(long)(d * 64 + r) * 928 + c] = 0;
    }
  }
}

// ---------------- ri GEMM ----------------
__global__ __launch_bounds__(256) void k_gemm_ri(const us* __restrict__ Ab,
    const us* __restrict__ Bb, const float* __restrict__ bias, float* __restrict__ ri) {
  int w = threadIdx.x >> 6, lane = threadIdx.x & 63;
  int lo = lane & 15, q = lane >> 4;
  int m0 = blockIdx.x * 16;
  f32x4 z = {0.f, 0.f, 0.f, 0.f};
  if (w < 3) {
    f32x4 acc[5] = {z, z, z, z, z};
    sweep<5>(Ab, 928, Bb, 928, m0, w * 5, lo, q, 0, 29, acc);
#pragma unroll
    for (int t2 = 0; t2 < 5; ++t2) {
      int col = (w * 5 + t2) * 16 + lo;
      if (col >= 300) continue;
      float bb = bias[col];
#pragma unroll
      for (int r = 0; r < 4; ++r)
        ri[(long)(m0 + q * 4 + r) * 300 + col] = lrelu(acc[t2][r] + bb);
    }
  } else {
    f32x4 acc[4] = {z, z, z, z};
    sweep<4>(Ab, 928, Bb, 928, m0, 15, lo, q, 0, 29, acc);
#pragma unroll
    for (int t2 = 0; t2 < 4; ++t2) {
      int col = (15 + t2) * 16 + lo;
      if (col >= 300) continue;
      float bb = bias[col];
#pragma unroll
      for (int r = 0; r < 4; ++r)
        ri[(long)(m0 + q * 4 + r) * 300 + col] = lrelu(acc[t2][r] + bb);
    }
  }
}

// ---------------- final ----------------
__global__ __launch_bounds__(256) void k_final(const float* __restrict__ ri,
    const float* __restrict__ W_cls, const float* __restrict__ b_cls,
    float* __restrict__ outp) {
  __shared__ float fin[300];
  __shared__ float red[256];
  int d = blockIdx.x, t = threadIdx.x;
  for (int h = t; h < 300; h += 256) {
    float s = 0.f;
    for (int i = 0; i < 64; ++i) s += ri[((d * 64) + i) * 300 + h];
    fin[h] = s * (1.0f / 64.0f);
  }
  __syncthreads();
  for (int c2 = 0; c2 < 2; ++c2) {
    float pth = 0.f;
    for (int h = t; h < 300; h += 256) pth = fmaf(fin[h], W_cls[c2 * 300 + h], pth);
    red[t] = pth;
    __syncthreads();
    for (int o = 128; o > 0; o >>= 1) {
      if (t < o) red[t] += red[t + o];
      __syncthreads();
    }
    if (t == 0) outp[d * 2 + c2] = red[0] + b_cls[c2];
    __syncthreads();
  }
}

extern "C" void kernel_launch(void* const* d_in, const int* in_sizes, int n_in,
                              void* d_out, int out_size, void* d_ws, size_t ws_size,
                              hipStream_t stream) {
  const int*   wi     = (const int*)d_in[0];
  const float* E      = (const float*)d_in[1];
  const float* W_sent = (const float*)d_in[2];
  const float* b_sent = (const float*)d_in[3];
  const float* W_par  = (const float*)d_in[4];
  const float* b_par  = (const float*)d_in[5];
  const float* W_ch   = (const float*)d_in[6];
  const float* b_ch   = (const float*)d_in[7];
  const float* w_root = (const float*)d_in[8];
  const float* b_root = (const float*)d_in[9];
  const float* root_e = (const float*)d_in[10];
  const float* W_r    = (const float*)d_in[11];
  const float* b_r    = (const float*)d_in[12];
  const float* W_cls  = (const float*)d_in[13];
  const float* b_cls  = (const float*)d_in[14];

  us* B = (us*)d_ws;
  us* Wsb   = B;                 //  97280   [304][320]
  us* Wpb   = B + 97280;
  us* Wcb   = B + 194560;
  us* Wrb   = B + 291840;        // 282112   [304][928]
  us* xg    = B + 573952;        // 1310720  [4096][320]
  us* encb  = B + 1884672;       // 1310720
  us* encTb = B + 3195392;       // 1245184  [304][4096]
  us* Pb    = B + 4440576;       // 1310720
  us* Cb    = B + 5751296;       // 1310720
  us* ub    = B + 7062016;       // 3801088  [4096][928]
  us* Atb   = B + 10863104;      // 262144   [64] x [64][64] bf16 A^T
  float* rsp = (float*)(B + 11125248);   // [64][4][64] fp32 partial rowsums
  float* ri  = (float*)(B + 11157760);   // [4096][300] fp32

  float* outp = (float*)d_out;   // [out(128) | A(262144) | fri(4096)]
  float* outA = outp + 128;
  float* outF = outp + 128 + 262144;

  k_prep<<<dim3(640, 7), 256, 0, stream>>>(wi, E, W_sent, W_par, W_ch, W_r,
                                           Wsb, Wpb, Wcb, Wrb, xg, encb, Pb, Cb, encTb);
  k_gemm_enc<<<256, 256, 0, stream>>>(xg, Wsb, b_sent, encb, encTb);
  k_gemm_pc<<<dim3(256, 2), 256, 0, stream>>>(encb, Wpb, Wcb, b_par, b_ch, Pb, Cb);
  k_attn<<<dim3(64, 4), 256, 0, stream>>>(Pb, Cb, encb, w_root, b_root,
                                          outA, outF, Atb, rsp);
  k_glue2<<<dim3(64, 5), 256, 0, stream>>>(Atb, encTb, encb, outF, rsp, root_e, ub);
  k_gemm_ri<<<256, 256, 0, stream>>>(ub, Wrb, b_r, ri);
  k_final<<<64, 256, 0, stream>>>(ri, W_cls, b_cls, outp);
}

// Round 9
// 189.005 us; speedup vs baseline: 1.1201x; 1.0137x over previous
//
#include <hip/hip_runtime.h>
#include <hip/hip_bf16.h>

#define NEG_INF (-9999999.0f)

typedef __attribute__((ext_vector_type(8))) short bf16x8;
typedef __attribute__((ext_vector_type(4))) float f32x4;
typedef unsigned short us;

__device__ __forceinline__ float b2f(us u) {
  union { unsigned int i; float f; } x; x.i = ((unsigned int)u) << 16; return x.f;
}
__device__ __forceinline__ us f2b(float f) {
  union { float f; unsigned int i; } x; x.f = f;
  unsigned int r = x.i + 0x7fffu + ((x.i >> 16) & 1u);
  return (us)(r >> 16);
}
__device__ __forceinline__ float lrelu(float v) { return v > 0.f ? v : 0.01f * v; }
__device__ __forceinline__ bf16x8 ld8(const us* p) { return *reinterpret_cast<const bf16x8*>(p); }

// ---------------- prep ----------------
__global__ __launch_bounds__(256) void k_prep(const int* __restrict__ wi, const float* __restrict__ E,
    const float* __restrict__ Ws, const float* __restrict__ Wp, const float* __restrict__ Wc,
    const float* __restrict__ Wr,
    us* __restrict__ Wsb, us* __restrict__ Wpb, us* __restrict__ Wcb, us* __restrict__ Wrb,
    us* __restrict__ xg, us* __restrict__ encb, us* __restrict__ Pb, us* __restrict__ Cb,
    us* __restrict__ encTb) {
  int task = blockIdx.y;
  int gid = blockIdx.x * 256 + threadIdx.x;
  const int stride = 640 * 256;
  if (task < 3) {
    const float* src = (task == 0) ? Ws : (task == 1) ? Wp : Wc;
    us* dst = (task == 0) ? Wsb : (task == 1) ? Wpb : Wcb;
    for (int i = gid; i < 304 * 320; i += stride) {
      int r = i / 320, c = i - r * 320;
      dst[i] = (r < 300 && c < 300) ? f2b(src[r * 300 + c]) : 0;
    }
  } else if (task == 3) {
    for (int i = gid; i < 304 * 928; i += stride) {
      int r = i / 928, c = i - r * 928;
      Wrb[i] = (r < 300 && c < 900) ? f2b(Wr[r * 900 + c]) : 0;
    }
  } else if (task == 4) {
    for (int i = gid; i < 4096 * 320; i += stride) {
      int r = i / 320, c = i - r * 320;
      xg[i] = (c < 300) ? f2b(E[(long)wi[r * 64 + 63] * 300 + c]) : 0;
    }
  } else if (task == 5) {
    for (int i = gid; i < 3 * 4096 * 20; i += stride) {
      int b = i / 81920, rem = i - b * 81920;
      int r = rem / 20, c = 300 + (rem - r * 20);
      us* dst = (b == 0) ? encb : (b == 1) ? Pb : Cb;
      dst[r * 320 + c] = 0;
    }
  } else {
    for (int i = gid; i < 4 * 4096; i += stride)
      encTb[300 * 4096 + i] = 0;
  }
}

// ---------------- stage a contiguous panel (units x 16B) into LDS ----------------
__device__ __forceinline__ void stage16(const us* __restrict__ g, us* lds, int units, int t) {
  const float4* s = reinterpret_cast<const float4*>(g);
  float4* d = reinterpret_cast<float4*>(lds);
  for (int i = t; i < units; i += 256) d[i] = s[i];
}

// ---------------- sweep with A from LDS (1-ahead), B from global (depth-3) ----------------
template<int NT, int KP>
__device__ __forceinline__ void sweep_lds(const us* As, const us* __restrict__ Bb,
    int bpitch, int nt0, int lo, int q, int ksn, f32x4* acc) {
  const us* ar = As + lo * KP + 8 * q;
  const us* br[NT];
#pragma unroll
  for (int t = 0; t < NT; ++t)
    br[t] = Bb + (long)((nt0 + t) * 16 + lo) * bpitch + 8 * q;
  bf16x8 b0[NT], b1[NT], b2[NT];
#pragma unroll
  for (int t = 0; t < NT; ++t) b0[t] = ld8(br[t]);
#pragma unroll
  for (int t = 0; t < NT; ++t) b1[t] = ld8(br[t] + 32);
#pragma unroll
  for (int t = 0; t < NT; ++t) b2[t] = ld8(br[t] + 64);
  bf16x8 a0 = *reinterpret_cast<const bf16x8*>(ar);
  for (int ks = 0; ks < ksn - 3; ++ks) {
    bf16x8 a1 = *reinterpret_cast<const bf16x8*>(ar + (ks + 1) * 32);
    bf16x8 bn[NT];
#pragma unroll
    for (int t = 0; t < NT; ++t) bn[t] = ld8(br[t] + (ks + 3) * 32);
#pragma unroll
    for (int t = 0; t < NT; ++t)
      acc[t] = __builtin_amdgcn_mfma_f32_16x16x32_bf16(a0, b0[t], acc[t], 0, 0, 0);
    a0 = a1;
#pragma unroll
    for (int t = 0; t < NT; ++t) { b0[t] = b1[t]; b1[t] = b2[t]; b2[t] = bn[t]; }
  }
  // tail 3 (no more B loads)
  {
    bf16x8 a1 = *reinterpret_cast<const bf16x8*>(ar + (ksn - 2) * 32);
#pragma unroll
    for (int t = 0; t < NT; ++t)
      acc[t] = __builtin_amdgcn_mfma_f32_16x16x32_bf16(a0, b0[t], acc[t], 0, 0, 0);
    a0 = a1;
#pragma unroll
    for (int t = 0; t < NT; ++t) b0[t] = b1[t];
  }
  {
    bf16x8 a1 = *reinterpret_cast<const bf16x8*>(ar + (ksn - 1) * 32);
#pragma unroll
    for (int t = 0; t < NT; ++t)
      acc[t] = __builtin_amdgcn_mfma_f32_16x16x32_bf16(a0, b0[t], acc[t], 0, 0, 0);
    a0 = a1;
#pragma unroll
    for (int t = 0; t < NT; ++t) b0[t] = b2[t];
  }
#pragma unroll
  for (int t = 0; t < NT; ++t)
    acc[t] = __builtin_amdgcn_mfma_f32_16x16x32_bf16(a0, b0[t], acc[t], 0, 0, 0);
}

// ---------------- global-load sweep (depth-2) — used by k_attn ----------------
template<int NT>
__device__ __forceinline__ void sweep(const us* __restrict__ Ab, int apitch,
    const us* __restrict__ Bb, int bpitch, int m0, int nt0, int lo, int q,
    int ks0, int ksn, f32x4* acc) {
  const us* ar = Ab + (long)(m0 + lo) * apitch + 8 * q + (long)ks0 * 32;
  const us* br[NT];
#pragma unroll
  for (int t = 0; t < NT; ++t)
    br[t] = Bb + (long)((nt0 + t) * 16 + lo) * bpitch + 8 * q + (long)ks0 * 32;
  bf16x8 a0 = ld8(ar), a1 = ld8(ar + 32);
  bf16x8 b0[NT], b1[NT];
#pragma unroll
  for (int t = 0; t < NT; ++t) b0[t] = ld8(br[t]);
#pragma unroll
  for (int t = 0; t < NT; ++t) b1[t] = ld8(br[t] + 32);
  for (int ks = 0; ks < ksn - 2; ++ks) {
    bf16x8 a2 = ld8(ar + (ks + 2) * 32);
    bf16x8 b2[NT];
#pragma unroll
    for (int t = 0; t < NT; ++t) b2[t] = ld8(br[t] + (ks + 2) * 32);
#pragma unroll
    for (int t = 0; t < NT; ++t)
      acc[t] = __builtin_amdgcn_mfma_f32_16x16x32_bf16(a0, b0[t], acc[t], 0, 0, 0);
    a0 = a1; a1 = a2;
#pragma unroll
    for (int t = 0; t < NT; ++t) { b0[t] = b1[t]; b1[t] = b2[t]; }
  }
#pragma unroll
  for (int t = 0; t < NT; ++t)
    acc[t] = __builtin_amdgcn_mfma_f32_16x16x32_bf16(a0, b0[t], acc[t], 0, 0, 0);
#pragma unroll
  for (int t = 0; t < NT; ++t)
    acc[t] = __builtin_amdgcn_mfma_f32_16x16x32_bf16(a1, b1[t], acc[t], 0, 0, 0);
}

template<int NT>
__device__ __forceinline__ void epi_bf16(const f32x4* acc, const float* __restrict__ bias,
    us* __restrict__ outb, us* __restrict__ outT,
    int m0, int nt0, int lo, int q) {
#pragma unroll
  for (int t = 0; t < NT; ++t) {
    int col = (nt0 + t) * 16 + lo;
    if (col >= 300) continue;
    float bb = bias[col];
#pragma unroll
    for (int r = 0; r < 4; ++r) {
      int row = m0 + q * 4 + r;
      us h = f2b(lrelu(acc[t][r] + bb));
      outb[(long)row * 320 + col] = h;
      if (outT) outT[(long)col * 4096 + row] = h;
    }
  }
}

// ---------------- enc GEMM: LDS A panel ----------------
__global__ __launch_bounds__(256) void k_gemm_enc(const us* __restrict__ Ab,
    const us* __restrict__ Bb, const float* __restrict__ bias,
    us* __restrict__ encb, us* __restrict__ encTb) {
  __shared__ __align__(16) us As[16 * 320];
  int t = threadIdx.x;
  int m0 = blockIdx.x * 16;
  stage16(Ab + (long)m0 * 320, As, 640, t);
  __syncthreads();
  int w = t >> 6, lane = t & 63, lo = lane & 15, q = lane >> 4;
  f32x4 z = {0.f, 0.f, 0.f, 0.f};
  if (w < 3) {
    f32x4 acc[5] = {z, z, z, z, z};
    sweep_lds<5, 320>(As, Bb, 320, w * 5, lo, q, 10, acc);
    epi_bf16<5>(acc, bias, encb, encTb, m0, w * 5, lo, q);
  } else {
    f32x4 acc[4] = {z, z, z, z};
    sweep_lds<4, 320>(As, Bb, 320, 15, lo, q, 10, acc);
    epi_bf16<4>(acc, bias, encb, encTb, m0, 15, lo, q);
  }
}

// ---------------- P/C GEMM: LDS A panel ----------------
__global__ __launch_bounds__(256) void k_gemm_pc(const us* __restrict__ Ab,
    const us* __restrict__ Wpb, const us* __restrict__ Wcb,
    const float* __restrict__ bp, const float* __restrict__ bc,
    us* __restrict__ Pb, us* __restrict__ Cb) {
  __shared__ __align__(16) us As[16 * 320];
  int which = blockIdx.y;
  const us* Bb = which ? Wcb : Wpb;
  const float* bias = which ? bc : bp;
  us* outb = which ? Cb : Pb;
  int t = threadIdx.x;
  int m0 = blockIdx.x * 16;
  stage16(Ab + (long)m0 * 320, As, 640, t);
  __syncthreads();
  int w = t >> 6, lane = t & 63, lo = lane & 15, q = lane >> 4;
  f32x4 z = {0.f, 0.f, 0.f, 0.f};
  if (w < 3) {
    f32x4 acc[5] = {z, z, z, z, z};
    sweep_lds<5, 320>(As, Bb, 320, w * 5, lo, q, 10, acc);
    epi_bf16<5>(acc, bias, outb, (us*)nullptr, m0, w * 5, lo, q);
  } else {
    f32x4 acc[4] = {z, z, z, z};
    sweep_lds<4, 320>(As, Bb, 320, 15, lo, q, 10, acc);
    epi_bf16<4>(acc, bias, outb, (us*)nullptr, m0, 15, lo, q);
  }
}

// ---------------- attn: block (d, jg) owns a 64x16 logit slab; local column softmax ----------------
__global__ __launch_bounds__(256) void k_attn(
    const us* __restrict__ Pb, const us* __restrict__ Cb, const us* __restrict__ encb,
    const float* __restrict__ w_root, const float* __restrict__ b_root,
    float* __restrict__ Aout, float* __restrict__ outF,
    us* __restrict__ Atb, float* __restrict__ rsp) {
  __shared__ float Ls[64][17];
  __shared__ float pm[4][16], psum[4][16];
  __shared__ float scores[64];
  int d = blockIdx.x, jg = blockIdx.y, t = threadIdx.x;
  int w = t >> 6, lane = t & 63, lo = lane & 15, q = lane >> 4;

  // fri (only jg==0 blocks; block-uniform branch)
  if (jg == 0) {
    int rr = t >> 2, quad = t & 3;
    const us* er = encb + (long)(d * 64 + rr) * 320;
    float s = 0.f;
    for (int h = quad * 4; h + 4 <= 300; h += 16) {
      ushort4 e4 = *reinterpret_cast<const ushort4*>(er + h);
      s = fmaf(b2f(e4.x), w_root[h], s);
      s = fmaf(b2f(e4.y), w_root[h + 1], s);
      s = fmaf(b2f(e4.z), w_root[h + 2], s);
      s = fmaf(b2f(e4.w), w_root[h + 3], s);
    }
    s += __shfl_xor(s, 1);
    s += __shfl_xor(s, 2);
    if (quad == 0) scores[rr] = s + b_root[0];
    __syncthreads();
    if (t < 64) {
      float sc = scores[t];
      float m = sc;
#pragma unroll
      for (int o = 32; o > 0; o >>= 1) m = fmaxf(m, __shfl_xor(m, o, 64));
      float e = expf(sc - m);
      float sum = e;
#pragma unroll
      for (int o = 32; o > 0; o >>= 1) sum += __shfl_xor(sum, o, 64);
      outF[d * 64 + t] = e / sum;
    }
  }

  // logits: wave w -> m-tile w, single n-tile jg
  {
    const us* Pd = Pb + (long)d * 64 * 320;
    const us* Cd = Cb + (long)d * 64 * 320;
    f32x4 acc = {0.f, 0.f, 0.f, 0.f};
    sweep<1>(Pd, 320, Cd, 320, w * 16, jg, lo, q, 0, 10, &acc);
#pragma unroll
    for (int r = 0; r < 4; ++r) {
      int i = w * 16 + q * 4 + r, j = jg * 16 + lo;
      Ls[i][lo] = (i == j) ? NEG_INF : acc[r];
    }
  }
  __syncthreads();

  // column softmax over i, 16 columns
  {
    int col = t & 15, p = t >> 4;
    if (t < 64) {
      float mx = -3.0e38f;
      for (int i = p * 16; i < p * 16 + 16; ++i) mx = fmaxf(mx, Ls[i][col]);
      pm[p][col] = mx;
    }
    __syncthreads();
    if (t < 64) {
      float gmx = fmaxf(fmaxf(pm[0][col], pm[1][col]), fmaxf(pm[2][col], pm[3][col]));
      float s = 0.f;
      for (int i = p * 16; i < p * 16 + 16; ++i) s += expf(Ls[i][col] - gmx);
      psum[p][col] = s;
    }
    __syncthreads();
    if (t < 64) {
      float gmx = fmaxf(fmaxf(pm[0][col], pm[1][col]), fmaxf(pm[2][col], pm[3][col]));
      float inv = 1.f / (psum[0][col] + psum[1][col] + psum[2][col] + psum[3][col]);
      int j = jg * 16 + col;
      float* Ad = Aout + (long)d * 4096;
      us* Atd = Atb + (long)d * 4096;
      for (int i = p * 16; i < p * 16 + 16; ++i) {
        float a = expf(Ls[i][col] - gmx) * inv;
        Ad[i * 64 + j] = a;
        Atd[j * 64 + i] = f2b(a);   // At[x][y] = A[y][x]
        Ls[i][col] = a;
      }
    }
  }
  __syncthreads();
  if (t < 64) {
    float s = 0.f;
#pragma unroll
    for (int c = 0; c < 16; ++c) s += Ls[t][c];
    rsp[(d * 4 + jg) * 64 + t] = s;
  }
}

// ---------------- glue2: block (d, g); wave w -> h-tile g*4+w; 60-col seg0/seg2 slice ----------------
__global__ __launch_bounds__(256) void k_glue2(
    const us* __restrict__ Atb, const us* __restrict__ encTb, const us* __restrict__ encb,
    const float* __restrict__ outF, const float* __restrict__ rsp,
    const float* __restrict__ root, us* __restrict__ ub) {
  __shared__ float frs[64], rs[64];
  int d = blockIdx.x, g = blockIdx.y, t = threadIdx.x;
  if (t < 64) {
    frs[t] = outF[d * 64 + t];
    rs[t] = rsp[(d * 4 + 0) * 64 + t] + rsp[(d * 4 + 1) * 64 + t]
          + rsp[(d * 4 + 2) * 64 + t] + rsp[(d * 4 + 3) * 64 + t];
  }
  __syncthreads();
  int w = t >> 6, lane = t & 63, lo = lane & 15, q = lane >> 4;
  int ht = g * 4 + w;
  if (ht < 19) {
    const us* Atd = Atb + (long)d * 4096;
    bf16x8 av0[4], av1[4];
#pragma unroll
    for (int mt = 0; mt < 4; ++mt) {
      av0[mt] = ld8(Atd + (mt * 16 + lo) * 64 + 8 * q);
      av1[mt] = ld8(Atd + (mt * 16 + lo) * 64 + 32 + 8 * q);
    }
    const us* brow = encTb + (long)(ht * 16 + lo) * 4096 + d * 64 + 8 * q;
    bf16x8 bv0 = ld8(brow), bv1 = ld8(brow + 32);
    int h = ht * 16 + lo;
    float rt = (h < 300) ? root[h] : 0.f;
#pragma unroll
    for (int mt = 0; mt < 4; ++mt) {
      f32x4 acc = {0.f, 0.f, 0.f, 0.f};
      acc = __builtin_amdgcn_mfma_f32_16x16x32_bf16(av0[mt], bv0, acc, 0, 0, 0);
      acc = __builtin_amdgcn_mfma_f32_16x16x32_bf16(av1[mt], bv1, acc, 0, 0, 0);
      if (h < 300) {
#pragma unroll
        for (int r = 0; r < 4; ++r) {
          int i = mt * 16 + q * 4 + r;
          ub[(long)(d * 64 + i) * 928 + 300 + h] = f2b(acc[r] + frs[i] * rt);
        }
      }
    }
  }
  for (int idx = t; idx < 64 * 60; idx += 256) {
    int r = idx / 60, c = g * 60 + (idx - (idx / 60) * 60);
    us ev = encb[(long)(d * 64 + r) * 320 + c];
    ub[(long)(d * 64 + r) * 928 + c] = ev;
    ub[(long)(d * 64 + r) * 928 + 600 + c] = f2b(b2f(ev) * rs[r]);
  }
  if (g == 4) {
    for (int idx = t; idx < 64 * 28; idx += 256) {
      int r = idx / 28, c = 900 + (idx - r * 28);
      ub[(long)(d * 64 + r) * 928 + c] = 0;
    }
  }
}

// ---------------- ri GEMM: LDS A panel (29 KB), K=29 ----------------
__global__ __launch_bounds__(256) void k_gemm_ri(const us* __restrict__ Ab,
    const us* __restrict__ Bb, const float* __restrict__ bias, float* __restrict__ ri) {
  __shared__ __align__(16) us As[16 * 928];
  int t = threadIdx.x;
  int m0 = blockIdx.x * 16;
  stage16(Ab + (long)m0 * 928, As, 1856, t);
  __syncthreads();
  int w = t >> 6, lane = t & 63, lo = lane & 15, q = lane >> 4;
  f32x4 z = {0.f, 0.f, 0.f, 0.f};
  if (w < 3) {
    f32x4 acc[5] = {z, z, z, z, z};
    sweep_lds<5, 928>(As, Bb, 928, w * 5, lo, q, 29, acc);
#pragma unroll
    for (int t2 = 0; t2 < 5; ++t2) {
      int col = (w * 5 + t2) * 16 + lo;
      if (col >= 300) continue;
      float bb = bias[col];
#pragma unroll
      for (int r = 0; r < 4; ++r)
        ri[(long)(m0 + q * 4 + r) * 300 + col] = lrelu(acc[t2][r] + bb);
    }
  } else {
    f32x4 acc[4] = {z, z, z, z};
    sweep_lds<4, 928>(As, Bb, 928, 15, lo, q, 29, acc);
#pragma unroll
    for (int t2 = 0; t2 < 4; ++t2) {
      int col = (15 + t2) * 16 + lo;
      if (col >= 300) continue;
      float bb = bias[col];
#pragma unroll
      for (int r = 0; r < 4; ++r)
        ri[(long)(m0 + q * 4 + r) * 300 + col] = lrelu(acc[t2][r] + bb);
    }
  }
}

// ---------------- final ----------------
__global__ __launch_bounds__(256) void k_final(const float* __restrict__ ri,
    const float* __restrict__ W_cls, const float* __restrict__ b_cls,
    float* __restrict__ outp) {
  __shared__ float fin[300];
  __shared__ float red[256];
  int d = blockIdx.x, t = threadIdx.x;
  for (int h = t; h < 300; h += 256) {
    float s = 0.f;
    for (int i = 0; i < 64; ++i) s += ri[((d * 64) + i) * 300 + h];
    fin[h] = s * (1.0f / 64.0f);
  }
  __syncthreads();
  for (int c2 = 0; c2 < 2; ++c2) {
    float pth = 0.f;
    for (int h = t; h < 300; h += 256) pth = fmaf(fin[h], W_cls[c2 * 300 + h], pth);
    red[t] = pth;
    __syncthreads();
    for (int o = 128; o > 0; o >>= 1) {
      if (t < o) red[t] += red[t + o];
      __syncthreads();
    }
    if (t == 0) outp[d * 2 + c2] = red[0] + b_cls[c2];
    __syncthreads();
  }
}

extern "C" void kernel_launch(void* const* d_in, const int* in_sizes, int n_in,
                              void* d_out, int out_size, void* d_ws, size_t ws_size,
                              hipStream_t stream) {
  const int*   wi     = (const int*)d_in[0];
  const float* E      = (const float*)d_in[1];
  const float* W_sent = (const float*)d_in[2];
  const float* b_sent = (const float*)d_in[3];
  const float* W_par  = (const float*)d_in[4];
  const float* b_par  = (const float*)d_in[5];
  const float* W_ch   = (const float*)d_in[6];
  const float* b_ch   = (const float*)d_in[7];
  const float* w_root = (const float*)d_in[8];
  const float* b_root = (const float*)d_in[9];
  const float* root_e = (const float*)d_in[10];
  const float* W_r    = (const float*)d_in[11];
  const float* b_r    = (const float*)d_in[12];
  const float* W_cls  = (const float*)d_in[13];
  const float* b_cls  = (const float*)d_in[14];

  us* B = (us*)d_ws;
  us* Wsb   = B;                 //  97280   [304][320]
  us* Wpb   = B + 97280;
  us* Wcb   = B + 194560;
  us* Wrb   = B + 291840;        // 282112   [304][928]
  us* xg    = B + 573952;        // 1310720  [4096][320]
  us* encb  = B + 1884672;       // 1310720
  us* encTb = B + 3195392;       // 1245184  [304][4096]
  us* Pb    = B + 4440576;       // 1310720
  us* Cb    = B + 5751296;       // 1310720
  us* ub    = B + 7062016;       // 3801088  [4096][928]
  us* Atb   = B + 10863104;      // 262144   [64] x [64][64] bf16 A^T
  float* rsp = (float*)(B + 11125248);   // [64][4][64] fp32 partial rowsums
  float* ri  = (float*)(B + 11157760);   // [4096][300] fp32

  float* outp = (float*)d_out;   // [out(128) | A(262144) | fri(4096)]
  float* outA = outp + 128;
  float* outF = outp + 128 + 262144;

  k_prep<<<dim3(640, 7), 256, 0, stream>>>(wi, E, W_sent, W_par, W_ch, W_r,
                                           Wsb, Wpb, Wcb, Wrb, xg, encb, Pb, Cb, encTb);
  k_gemm_enc<<<256, 256, 0, stream>>>(xg, Wsb, b_sent, encb, encTb);
  k_gemm_pc<<<dim3(256, 2), 256, 0, stream>>>(encb, Wpb, Wcb, b_par, b_ch, Pb, Cb);
  k_attn<<<dim3(64, 4), 256, 0, stream>>>(Pb, Cb, encb, w_root, b_root,
                                          outA, outF, Atb, rsp);
  k_glue2<<<dim3(64, 5), 256, 0, stream>>>(Atb, encTb, encb, outF, rsp, root_e, ub);
  k_gemm_ri<<<256, 256, 0, stream>>>(ub, Wrb, b_r, ri);
  k_final<<<64, 256, 0, stream>>>(ri, W_cls, b_cls, outp);
}